// Round 18
// baseline (702.135 us; speedup 1.0000x reference)
//
#include <hip/hip_runtime.h>

typedef unsigned short u16;
typedef unsigned int   u32;
typedef __attribute__((ext_vector_type(8)))  __bf16 bf16x8;
typedef __attribute__((ext_vector_type(4)))  float  f32x4;
typedef __attribute__((ext_vector_type(16))) float  f32x16;

__device__ __forceinline__ float bf2f(u16 u) {
    union { u32 i; float f; } v; v.i = ((u32)u) << 16; return v.f;
}
__device__ __forceinline__ u16 f2bf(float f) {
    u32 u = __float_as_uint(f);
    u32 r = (u + 0x7FFFu + ((u >> 16) & 1u)) >> 16;
    return (u16)r;
}

__device__ __forceinline__ void gl16(const u16* g, u16* l) {
    __builtin_amdgcn_global_load_lds(
        (const __attribute__((address_space(1))) unsigned int*)g,
        (__attribute__((address_space(3))) unsigned int*)l, 16, 0, 0);
}

// ---------------------------------------------------------------------------
// Kernel 1: grouped directional conv 5x5, C=32 -> 256, pad=2, no bias.
// ---------------------------------------------------------------------------
__global__ __launch_bounds__(256) void dir_conv_k(const float* __restrict__ x,
                                                  const float* __restrict__ wd,
                                                  u16* __restrict__ coeffs) {
    int bid = blockIdx.x;
    int cc = bid & 3, y = (bid >> 2) & 127, n = bid >> 9;
    __shared__ float lx[5280];   // [8 c][5 ky][132 xx]
    __shared__ float lw[1600];   // [25 tap][64 oc_local]
    int t = threadIdx.x;
    for (int i = t; i < 1600; i += 256) {
        int ol = i / 25, tap = i - ol * 25;
        lw[tap * 64 + ol] = wd[(cc * 64 + ol) * 25 + tap];
    }
    for (int i = t; i < 5280; i += 256) {
        int c = i / 660, rem = i - c * 660;
        int ky = rem / 132, xx = rem - ky * 132;
        int gy = y - 2 + ky, gx = xx - 2;
        float v = 0.f;
        if (gy >= 0 && gy < 128 && gx >= 0 && gx < 128)
            v = x[(((n * 32 + cc * 8 + c) * 128 + gy) << 7) + gx];
        lx[i] = v;
    }
    __syncthreads();
    int px = t >> 1, oh = t & 1;
    float acc[4][8];
#pragma unroll
    for (int j = 0; j < 4; ++j)
#pragma unroll
        for (int d = 0; d < 8; ++d) acc[j][d] = 0.f;
#pragma unroll
    for (int j = 0; j < 4; ++j) {
        int cl = oh * 4 + j;
        const float* lxc = &lx[cl * 660];
#pragma unroll
        for (int ky = 0; ky < 5; ++ky)
#pragma unroll
            for (int kx = 0; kx < 5; ++kx) {
                float xv = lxc[ky * 132 + px + kx];
                const float* w8 = &lw[(ky * 5 + kx) * 64 + cl * 8];
#pragma unroll
                for (int d = 0; d < 8; ++d) acc[j][d] += xv * w8[d];
            }
    }
    long base = ((long)((n * 128 + y) * 128 + px)) * 256 + cc * 64 + oh * 32;
#pragma unroll
    for (int j = 0; j < 4; ++j) {
        uint4 o;
        o.x = (u32)f2bf(acc[j][0]) | ((u32)f2bf(acc[j][1]) << 16);
        o.y = (u32)f2bf(acc[j][2]) | ((u32)f2bf(acc[j][3]) << 16);
        o.z = (u32)f2bf(acc[j][4]) | ((u32)f2bf(acc[j][5]) << 16);
        o.w = (u32)f2bf(acc[j][6]) | ((u32)f2bf(acc[j][7]) << 16);
        *(uint4*)(coeffs + base + j * 8) = o;
    }
}

// ---------------------------------------------------------------------------
// Repack conv weights OIHW f32 -> 16x16x32 B-fragment-order bf16:
// wp[(((tap*KC+kc)*(OC/16)+ocg)*64 + l)*8 + j]
//   = w[oc = ocg*16 + (l&15)][ic = kc*32 + (l>>4)*8 + j][tap]
// (16x16x32 B layout verified empirically in round 1: k = (lane>>4)*8 + j,
//  col = lane&15.)
// ---------------------------------------------------------------------------
__global__ __launch_bounds__(256) void repack_w_k(const float* __restrict__ w,
                                                  u16* __restrict__ wp,
                                                  int OC, int IC, int total) {
    int f = blockIdx.x * 256 + threadIdx.x;
    if (f >= total) return;
    int KC = IC >> 5;
    int OG = OC >> 4;
    int j = f & 7;
    int l = (f >> 3) & 63;
    int g = f >> 9;            // (tap*KC+kc)*OG + ocg
    int ocg = g % OG; g /= OG;
    int kc = g % KC;
    int tap = g / KC;
    int oc = ocg * 16 + (l & 15);
    int ic = kc * 32 + (l >> 4) * 8 + j;
    wp[f] = f2bf(w[(oc * IC + ic) * 9 + tap]);
}

// ---------------------------------------------------------------------------
// 3x3 conv, NHWC bf16 in/out, implicit GEMM, mfma_f32_16x16x32_bf16.
// Same geometry as r13/r17 best (128px x 256oc block, 4 waves, wave tile
// 128px x 64oc, 2 waves/SIMD, 2 blocks/CU, dbuf LDS staging, 1 barrier/kc)
// but 16x16x32 MFMA: per K=32 tap the wave does 8 A ds_reads + 4 B loads
// (BYTE-IDENTICAL supply traffic to 32x32) feeding 32 MFMAs at ~155 CU-cyc
// vs 128 — LDS-pipe:MFMA-pipe ratio drops 75% -> 62%.
// Loop: 9 taps/kc; A+B 1-tap ping-pong; 9 odd -> parity alternates per kc,
// handled by kc-unroll x2 with compile-time OFF in {0,1}:
// use buf (i+OFF)&1, load tap (i+1)%9 into (i+1+OFF)&1.
// setprio around MFMA cluster. Fused BN-stats partials.
// ---------------------------------------------------------------------------
#define AREAD(P, lAu, DY, DX)                                                  \
    {                                                                          \
        int au_ = ((kq * 3 + (DY)) * W + (DX) + l15) * 8;                      \
        _Pragma("unroll")                                                      \
        for (int mf_ = 0; mf_ < 8; ++mf_)                                      \
            Ar[P][mf_] = *(const bf16x8*)((lAu) + au_ + mf_ * 128);            \
    }

#define MFMA32(P)                                                              \
    _Pragma("unroll")                                                          \
    for (int mf_ = 0; mf_ < 8; ++mf_) {                                        \
        acc[mf_][0] = __builtin_amdgcn_mfma_f32_16x16x32_bf16(Ar[P][mf_], Br[P][0], acc[mf_][0], 0, 0, 0); \
        acc[mf_][1] = __builtin_amdgcn_mfma_f32_16x16x32_bf16(Ar[P][mf_], Br[P][1], acc[mf_][1], 0, 0, 0); \
        acc[mf_][2] = __builtin_amdgcn_mfma_f32_16x16x32_bf16(Ar[P][mf_], Br[P][2], acc[mf_][2], 0, 0, 0); \
        acc[mf_][3] = __builtin_amdgcn_mfma_f32_16x16x32_bf16(Ar[P][mf_], Br[P][3], acc[mf_][3], 0, 0, 0); \
    }

#define KCITER(KCV, OFF)                                                       \
    {                                                                          \
        const int kc_ = (KCV);                                                 \
        const u16* lAu = (kc_ & 1) ? lA1 : lA0;                                \
        u16*       lAn = (kc_ & 1) ? lA0 : lA1;                                \
        __syncthreads();                                                       \
        AREAD((OFF), lAu, 0, 0);                                               \
        if (kc_ + 1 < KC) stage(lAn, kc_ + 1);                                 \
        _Pragma("unroll")                                                      \
        for (int i = 0; i < 9; ++i) {                                          \
            const int jt = (i + 1) % 9;                                        \
            const int jkc = (i == 8) ? ((kc_ + 1 < KC) ? kc_ + 1 : 0) : kc_;   \
            if (i != 8) AREAD(((i + 1 + (OFF)) & 1), lAu, (jt / 3), (jt % 3)); \
            bload(Br[(i + 1 + (OFF)) & 1], jt, jkc);                           \
            __builtin_amdgcn_s_setprio(1);                                     \
            MFMA32(((i + (OFF)) & 1));                                         \
            __builtin_amdgcn_s_setprio(0);                                     \
        }                                                                      \
    }

template<int IC, int OC>
__global__ __launch_bounds__(256, 2) void conv3_k(const u16* __restrict__ base,
                                                  u32 in_off,
                                                  const u16* __restrict__ wp,
                                                  const float* __restrict__ bias,
                                                  u32 zp_off,
                                                  u16* __restrict__ outp,
                                                  float* __restrict__ statp) {
    constexpr int KC = IC / 32;         // 8 or 16 — even (required by 2x unroll)
    constexpr int W  = 130;             // 128 px + halo
    constexpr int TU = 12 * W;          // 1560 16B staging units per buffer
    constexpr int NFULL = TU / 256;     // 6
    constexpr int REM   = TU % 256;     // 24
    __shared__ u16 lA0[TU * 8];
    __shared__ u16 lA1[TU * 8];

    int bx0 = blockIdx.x;
    int bx = ((bx0 & 7) << 7) + (bx0 >> 3);   // XCD swizzle (1024 % 8 == 0)
    int y = bx & 127, n = bx >> 7;
    int ocb = blockIdx.y;
    int t = threadIdx.x, lane = t & 63, wv = t >> 6;
    int l15 = lane & 15, kq = lane >> 4;
    int ocw = ocb * 256 + wv * 64;

    // per-lane staging source offsets (u16 units from `base`) — same as r13
    u32 off[NFULL + 1];
#pragma unroll
    for (int i = 0; i <= NFULL; ++i) {
        int u = (i == NFULL) ? (NFULL * 256 + lane) : (i * 256 + t);
        int icq = u / (3 * W);
        int r2  = u - icq * (3 * W);
        int dy  = r2 / W;
        int xx  = r2 - dy * W;
        int gy = y - 1 + dy, gx = xx - 1;
        bool ok = ((unsigned)gy < 128u) && ((unsigned)gx < 128u);
        off[i] = ok ? (in_off + (u32)((n * 128 + gy) * 128 + gx) * IC + (icq & 3) * 8)
                    : zp_off;
    }

    auto stage = [&](u16* dst, int kc) {
#pragma unroll
        for (int i = 0; i < NFULL; ++i)
            gl16(base + off[i] + kc * 32, dst + (i * 256 + wv * 64) * 8);
        if (wv == 0 && lane < REM)
            gl16(base + off[NFULL] + kc * 32, dst + NFULL * 256 * 8);
    };

    u32 wboff = (u32)(ocw >> 4) * 512 + (u32)lane * 8;
    bf16x8 Ar[2][8];
    bf16x8 Br[2][4];

    // B loader for tap jt (0..8) of chunk kcv: 4 oc-groups of 16
    auto bload = [&](bf16x8* dst, int jt, int kcv) {
        const u16* wb = wp + (u32)((jt * KC + kcv) * (OC >> 4)) * 512 + wboff;
        dst[0] = *(const bf16x8*)wb;
        dst[1] = *(const bf16x8*)(wb + 512);
        dst[2] = *(const bf16x8*)(wb + 1024);
        dst[3] = *(const bf16x8*)(wb + 1536);
    };

    // prologue: tap0 of kc=0 into Br[0] (OFF=0)
    bload(Br[0], 0, 0);

    f32x4 acc[8][4];
#pragma unroll
    for (int mf = 0; mf < 8; ++mf)
#pragma unroll
        for (int nf = 0; nf < 4; ++nf)
#pragma unroll
            for (int r = 0; r < 4; ++r) acc[mf][nf][r] = 0.f;

    stage(lA0, 0);
    for (int kcb = 0; kcb < KC; kcb += 2) {
        KCITER(kcb, 0);
        KCITER(kcb + 1, 1);
    }

    // epilogue: C layout (16x16, round-1-verified): oc = l&15, px = kq*4 + r
    long rowb = (long)(n * 128 + y) * 128;
    float ss[4] = {0.f, 0.f, 0.f, 0.f}, qq[4] = {0.f, 0.f, 0.f, 0.f};
#pragma unroll
    for (int nf = 0; nf < 4; ++nf) {
        int oc = ocw + nf * 16 + l15;
        float bi = bias[oc];
#pragma unroll
        for (int mf = 0; mf < 8; ++mf)
#pragma unroll
            for (int r = 0; r < 4; ++r) {
                int px = mf * 16 + kq * 4 + r;
                u16 bv = f2bf(acc[mf][nf][r] + bi);
                outp[(rowb + px) * OC + oc] = bv;
                float vr = bf2f(bv);
                ss[nf] += vr;
                qq[nf] += vr * vr;
            }
    }
#pragma unroll
    for (int nf = 0; nf < 4; ++nf) {
        ss[nf] += __shfl_xor(ss[nf], 16);
        ss[nf] += __shfl_xor(ss[nf], 32);
        qq[nf] += __shfl_xor(qq[nf], 16);
        qq[nf] += __shfl_xor(qq[nf], 32);
    }
    if (lane < 16) {
#pragma unroll
        for (int nf = 0; nf < 4; ++nf) {
            int oc = ocw + nf * 16 + lane;
            atomicAdd(&statp[oc * 2],     ss[nf]);
            atomicAdd(&statp[oc * 2 + 1], qq[nf]);
        }
    }
}

// Stage 2: per-channel affine (a, b): a*x+b == BN(x), from fused partials.
template<int C>
__global__ __launch_bounds__(256) void stats2_k(const float* __restrict__ part,
                                                const float* __restrict__ g,
                                                const float* __restrict__ be,
                                                float* __restrict__ ab) {
    int ch = blockIdx.x * 256 + threadIdx.x;
    if (ch >= C) return;
    float s = part[ch * 2], q = part[ch * 2 + 1];
    const float M = 131072.f;
    float mean = s / M;
    float var = q / M - mean * mean;
    float a = g[ch] * rsqrtf(var + 1e-5f);
    ab[ch * 2]     = a;
    ab[ch * 2 + 1] = be[ch] - mean * a;
}

// BN1 + ReLU in place on h1 (NHWC bf16, C=512). 8 elems/thread.
__global__ __launch_bounds__(256) void bn_relu_k(u16* __restrict__ h,
                                                 const float* __restrict__ ab) {
    long idx8 = (long)blockIdx.x * 256 + threadIdx.x;
    u16* p = h + idx8 * 8;
    uint4 v = *(const uint4*)p;
    int chb = ((int)idx8 & 63) << 3;
    u32 w[4] = {v.x, v.y, v.z, v.w};
    u32 o[4];
#pragma unroll
    for (int q = 0; q < 4; ++q) {
        int ch = chb + q * 2;
        float2 a0 = *(const float2*)(ab + ch * 2);
        float2 a1 = *(const float2*)(ab + ch * 2 + 2);
        float f0 = bf2f((u16)(w[q] & 0xffff));
        float f1 = bf2f((u16)(w[q] >> 16));
        f0 = fmaxf(f0 * a0.x + a0.y, 0.f);
        f1 = fmaxf(f1 * a1.x + a1.y, 0.f);
        o[q] = (u32)f2bf(f0) | ((u32)f2bf(f1) << 16);
    }
    *(uint4*)p = make_uint4(o[0], o[1], o[2], o[3]);
}

// ---------------------------------------------------------------------------
// Fused BN2+ReLU + 1x1 inverse conv via MFMA (M=131072 px, N=32 oc, K=256).
// (unchanged — 32x32x16 path, verified r10)
// ---------------------------------------------------------------------------
__global__ __launch_bounds__(256) void inv_conv_k(const u16* __restrict__ h2,
                                                  const float* __restrict__ ab,
                                                  const float* __restrict__ winv,
                                                  const float* __restrict__ binv,
                                                  float* __restrict__ out) {
    __shared__ float lab[512];
    int t = threadIdx.x, lane = t & 63, wv = t >> 6;
    int lm = lane & 31, h = lane >> 5;
    lab[t] = ab[t];
    lab[t + 256] = ab[t + 256];
    __syncthreads();

    bf16x8 B[16];
#pragma unroll
    for (int s = 0; s < 16; ++s) {
        const float* wsrc = winv + lm * 256 + s * 16 + h * 8;
        union { bf16x8 v; u16 a[8]; } cv;
#pragma unroll
        for (int j = 0; j < 8; ++j) cv.a[j] = f2bf(wsrc[j]);
        B[s] = cv.v;
    }

    long pxw = (long)blockIdx.x * 256 + wv * 64;
    const u16* a0p = h2 + (pxw + lm) * 256 + h * 8;
    const u16* a1p = a0p + 32 * 256;

    f32x16 acc0, acc1;
#pragma unroll
    for (int r = 0; r < 16; ++r) { acc0[r] = 0.f; acc1[r] = 0.f; }

#pragma unroll
    for (int s = 0; s < 16; ++s) {
        int k0 = s * 16 + h * 8;
        uint4 v0 = *(const uint4*)(a0p + s * 16);
        uint4 v1 = *(const uint4*)(a1p + s * 16);
        u32 w0[4] = {v0.x, v0.y, v0.z, v0.w};
        u32 w1[4] = {v1.x, v1.y, v1.z, v1.w};
        union { bf16x8 v; u16 a[8]; } A0, A1;
#pragma unroll
        for (int j = 0; j < 8; ++j) {
            float aab = lab[(k0 + j) * 2], bbb = lab[(k0 + j) * 2 + 1];
            u16 u0 = (j & 1) ? (u16)(w0[j >> 1] >> 16) : (u16)(w0[j >> 1] & 0xffff);
            u16 u1 = (j & 1) ? (u16)(w1[j >> 1] >> 16) : (u16)(w1[j >> 1] & 0xffff);
            A0.a[j] = f2bf(fmaxf(bf2f(u0) * aab + bbb, 0.f));
            A1.a[j] = f2bf(fmaxf(bf2f(u1) * aab + bbb, 0.f));
        }
        acc0 = __builtin_amdgcn_mfma_f32_32x32x16_bf16(A0.v, B[s], acc0, 0, 0, 0);
        acc1 = __builtin_amdgcn_mfma_f32_32x32x16_bf16(A1.v, B[s], acc1, 0, 0, 0);
    }

    float bi = binv[lm];
    int n = (int)(pxw >> 14);
    int prem = (int)(pxw & 16383);
    float* ob = out + (((long)(n * 32 + lm)) << 14) + prem + 4 * h;
#pragma unroll
    for (int g = 0; g < 4; ++g) {
        f32x4 o0, o1;
#pragma unroll
        for (int i = 0; i < 4; ++i) { o0[i] = acc0[g * 4 + i] + bi; o1[i] = acc1[g * 4 + i] + bi; }
        *(f32x4*)(ob + g * 8)      = o0;
        *(f32x4*)(ob + 32 + g * 8) = o1;
    }
}

// ---------------------------------------------------------------------------
// Workspace layout (bytes) — ~200 MiB:
//   0         w1p   (2,359,296)
//   2359296   w2p   (2,359,296)
//   4718592   part1 (4,096)  fused BN1 stats (s,q per oc)
//   4722688   part2 (2,048)  fused BN2 stats
//   5242880   ab1   (4,096)
//   5246976   ab2   (2,048)
//   5249024   zp    (1,024)  zero page for conv halo
//   8388608   coeffs / h2 (67,108,864)
//   75497472  h1    (134,217,728)
// ---------------------------------------------------------------------------
extern "C" void kernel_launch(void* const* d_in, const int* in_sizes, int n_in,
                              void* d_out, int out_size, void* d_ws, size_t ws_size,
                              hipStream_t stream) {
    const float* x     = (const float*)d_in[0];
    const float* w_dir = (const float*)d_in[1];
    const float* w1    = (const float*)d_in[2];
    const float* b1    = (const float*)d_in[3];
    const float* g1    = (const float*)d_in[4];
    const float* be1   = (const float*)d_in[5];
    const float* w2    = (const float*)d_in[6];
    const float* b2    = (const float*)d_in[7];
    const float* g2    = (const float*)d_in[8];
    const float* be2   = (const float*)d_in[9];
    const float* w_inv = (const float*)d_in[10];
    const float* b_inv = (const float*)d_in[11];
    float* out = (float*)d_out;
    char* ws = (char*)d_ws;

    u16*   w1p   = (u16*)(ws + 0);
    u16*   w2p   = (u16*)(ws + 2359296);
    float* part1 = (float*)(ws + 4718592);
    float* part2 = (float*)(ws + 4722688);
    float* ab1   = (float*)(ws + 5242880);
    float* ab2   = (float*)(ws + 5246976);
    u16*   zp    = (u16*)(ws + 5249024);
    u16*   coef  = (u16*)(ws + 8388608);     // also h2
    u16*   h1    = (u16*)(ws + 75497472);
    const u16* basep = (const u16*)ws;
    u32 zp_off   = 5249024 / 2;
    u32 coef_off = 8388608 / 2;
    u32 h1_off   = 75497472 / 2;

    hipMemsetAsync(zp, 0, 1024, stream);
    hipMemsetAsync(part1, 0, 8192, stream);   // covers part1 + part2
    repack_w_k<<<4608, 256, 0, stream>>>(w1, w1p, 512, 256, 1179648);
    repack_w_k<<<4608, 256, 0, stream>>>(w2, w2p, 256, 512, 1179648);
    dir_conv_k<<<4096, 256, 0, stream>>>(x, w_dir, coef);
    conv3_k<256, 512><<<dim3(1024, 2), 256, 0, stream>>>(basep, coef_off, w1p, b1, zp_off, h1, part1);
    stats2_k<512><<<2, 256, 0, stream>>>(part1, g1, be1, ab1);
    bn_relu_k<<<32768, 256, 0, stream>>>(h1, ab1);
    conv3_k<512, 256><<<dim3(1024, 1), 256, 0, stream>>>(basep, h1_off, w2p, b2, zp_off, coef, part2);
    stats2_k<256><<<1, 256, 0, stream>>>(part2, g2, be2, ab2);
    inv_conv_k<<<512, 256, 0, stream>>>(coef, ab2, w_inv, b_inv, out);
}

// Round 19
// 694.544 us; speedup vs baseline: 1.0109x; 1.0109x over previous
//
#include <hip/hip_runtime.h>

typedef unsigned short u16;
typedef unsigned int   u32;
typedef __attribute__((ext_vector_type(8)))  __bf16 bf16x8;
typedef __attribute__((ext_vector_type(4)))  float  f32x4;
typedef __attribute__((ext_vector_type(16))) float  f32x16;

__device__ __forceinline__ float bf2f(u16 u) {
    union { u32 i; float f; } v; v.i = ((u32)u) << 16; return v.f;
}
__device__ __forceinline__ u16 f2bf(float f) {
    u32 u = __float_as_uint(f);
    u32 r = (u + 0x7FFFu + ((u >> 16) & 1u)) >> 16;
    return (u16)r;
}

__device__ __forceinline__ void gl16(const u16* g, u16* l) {
    __builtin_amdgcn_global_load_lds(
        (const __attribute__((address_space(1))) unsigned int*)g,
        (__attribute__((address_space(3))) unsigned int*)l, 16, 0, 0);
}

// ---------------------------------------------------------------------------
// Kernel 1: grouped directional conv 5x5, C=32 -> 256, pad=2, no bias.
// ---------------------------------------------------------------------------
__global__ __launch_bounds__(256) void dir_conv_k(const float* __restrict__ x,
                                                  const float* __restrict__ wd,
                                                  u16* __restrict__ coeffs) {
    int bid = blockIdx.x;
    int cc = bid & 3, y = (bid >> 2) & 127, n = bid >> 9;
    __shared__ float lx[5280];   // [8 c][5 ky][132 xx]
    __shared__ float lw[1600];   // [25 tap][64 oc_local]
    int t = threadIdx.x;
    for (int i = t; i < 1600; i += 256) {
        int ol = i / 25, tap = i - ol * 25;
        lw[tap * 64 + ol] = wd[(cc * 64 + ol) * 25 + tap];
    }
    for (int i = t; i < 5280; i += 256) {
        int c = i / 660, rem = i - c * 660;
        int ky = rem / 132, xx = rem - ky * 132;
        int gy = y - 2 + ky, gx = xx - 2;
        float v = 0.f;
        if (gy >= 0 && gy < 128 && gx >= 0 && gx < 128)
            v = x[(((n * 32 + cc * 8 + c) * 128 + gy) << 7) + gx];
        lx[i] = v;
    }
    __syncthreads();
    int px = t >> 1, oh = t & 1;
    float acc[4][8];
#pragma unroll
    for (int j = 0; j < 4; ++j)
#pragma unroll
        for (int d = 0; d < 8; ++d) acc[j][d] = 0.f;
#pragma unroll
    for (int j = 0; j < 4; ++j) {
        int cl = oh * 4 + j;
        const float* lxc = &lx[cl * 660];
#pragma unroll
        for (int ky = 0; ky < 5; ++ky)
#pragma unroll
            for (int kx = 0; kx < 5; ++kx) {
                float xv = lxc[ky * 132 + px + kx];
                const float* w8 = &lw[(ky * 5 + kx) * 64 + cl * 8];
#pragma unroll
                for (int d = 0; d < 8; ++d) acc[j][d] += xv * w8[d];
            }
    }
    long base = ((long)((n * 128 + y) * 128 + px)) * 256 + cc * 64 + oh * 32;
#pragma unroll
    for (int j = 0; j < 4; ++j) {
        uint4 o;
        o.x = (u32)f2bf(acc[j][0]) | ((u32)f2bf(acc[j][1]) << 16);
        o.y = (u32)f2bf(acc[j][2]) | ((u32)f2bf(acc[j][3]) << 16);
        o.z = (u32)f2bf(acc[j][4]) | ((u32)f2bf(acc[j][5]) << 16);
        o.w = (u32)f2bf(acc[j][6]) | ((u32)f2bf(acc[j][7]) << 16);
        *(uint4*)(coeffs + base + j * 8) = o;
    }
}

// ---------------------------------------------------------------------------
// Repack conv weights OIHW f32 -> 32x32x16 B-fragment-order bf16:
// wp[((((tap*KC+kc)*2+s)*OC+oc)*2+h)*8 + j] = w[oc][kc*32+s*16+h*8+j][tap]
// ---------------------------------------------------------------------------
__global__ __launch_bounds__(256) void repack_w_k(const float* __restrict__ w,
                                                  u16* __restrict__ wp,
                                                  int OC, int IC, int total) {
    int f = blockIdx.x * 256 + threadIdx.x;
    if (f >= total) return;
    int KC = IC >> 5;
    int j  = f & 7;
    int h  = (f >> 3) & 1;
    int g  = f >> 4;           // ((tap*KC+kc)*2+s)*OC + oc
    int oc = g % OC; g /= OC;
    int s  = g & 1;  g >>= 1;  // tap*KC + kc
    int kc = g % KC;
    int tap = g / KC;
    int ic = kc * 32 + s * 16 + h * 8 + j;
    wp[f] = f2bf(w[(oc * IC + ic) * 9 + tap]);
}

// ---------------------------------------------------------------------------
// 3x3 conv, NHWC bf16 in/out, implicit GEMM, mfma_f32_32x32x16_bf16.
// Block: 128 px (one image row) x 256 oc; 4 waves, wave tile 128px x 64oc
// (acc[4][2]); 2 waves/SIMD. A: dbuf LDS via global_load_lds, 1 barrier/kc.
// Inner: A 1-subk ping-pong; B 4-slot rotation with 3-subk lead. Slot index
// is CONTINUOUS in i: use Br[(i+OFF)&3], load subk (i+3)%18 into
// Br[(i+3+OFF)&3]. kc loop unrolled x2 with OFF in {0,2} since 18%4==2.
// setprio around MFMA cluster (r14/r15 A/B: removal costs ~33 µs/conv —
// 2 async blocks/CU give cross-block wave role diversity).
// Fused BN-stats partials (atomicAdd into statp, pre-zeroed).
// FINAL CONFIG: best of 18 structural variants (295 µs, 49.9% MfmaUtil,
// 0 bank conflicts); 16x16 shape, tile transpose, 8-phase, occupancy and
// B-lead variants all measured worse. See session journal.
// ---------------------------------------------------------------------------
#define KCITER(KCV, OFF)                                                       \
    {                                                                          \
        const int kc_ = (KCV);                                                 \
        const u16* lAu = (kc_ & 1) ? lA1 : lA0;                                \
        u16*       lAn = (kc_ & 1) ? lA0 : lA1;                                \
        __syncthreads();                                                       \
        {                                                                      \
            int au = ((h * 3) * W + lm) * 8;                                   \
            Ar[0][0] = *(const bf16x8*)(lAu + au);                             \
            Ar[0][1] = *(const bf16x8*)(lAu + au + 256);                       \
            Ar[0][2] = *(const bf16x8*)(lAu + au + 512);                       \
            Ar[0][3] = *(const bf16x8*)(lAu + au + 768);                       \
        }                                                                      \
        if (kc_ + 1 < KC) stage(lAn, kc_ + 1);                                 \
        _Pragma("unroll")                                                      \
        for (int i = 0; i < 18; ++i) {                                         \
            const int j   = (i + 1) % 18;        /* A: 1 subk ahead */         \
            const int j3  = (i + 3) % 18;        /* B: 3 subks ahead */        \
            const int j3kc = (i >= 15) ? ((kc_ + 1 < KC) ? kc_ + 1 : 0) : kc_; \
            if (i != 17) {                                                     \
                const int jdy = j / 6, jdx = (j % 6) >> 1, js = j & 1;         \
                int au = (((js * 2 + h) * 3 + jdy) * W + jdx + lm) * 8;        \
                Ar[j & 1][0] = *(const bf16x8*)(lAu + au);                     \
                Ar[j & 1][1] = *(const bf16x8*)(lAu + au + 256);               \
                Ar[j & 1][2] = *(const bf16x8*)(lAu + au + 512);               \
                Ar[j & 1][3] = *(const bf16x8*)(lAu + au + 768);               \
            }                                                                  \
            bload(Br[(i + 3 + (OFF)) & 3], j3, j3kc);                          \
            __builtin_amdgcn_s_setprio(1);                                     \
            acc[0][0] = __builtin_amdgcn_mfma_f32_32x32x16_bf16(Ar[i & 1][0], Br[(i + (OFF)) & 3][0], acc[0][0], 0, 0, 0); \
            acc[0][1] = __builtin_amdgcn_mfma_f32_32x32x16_bf16(Ar[i & 1][0], Br[(i + (OFF)) & 3][1], acc[0][1], 0, 0, 0); \
            acc[1][0] = __builtin_amdgcn_mfma_f32_32x32x16_bf16(Ar[i & 1][1], Br[(i + (OFF)) & 3][0], acc[1][0], 0, 0, 0); \
            acc[1][1] = __builtin_amdgcn_mfma_f32_32x32x16_bf16(Ar[i & 1][1], Br[(i + (OFF)) & 3][1], acc[1][1], 0, 0, 0); \
            acc[2][0] = __builtin_amdgcn_mfma_f32_32x32x16_bf16(Ar[i & 1][2], Br[(i + (OFF)) & 3][0], acc[2][0], 0, 0, 0); \
            acc[2][1] = __builtin_amdgcn_mfma_f32_32x32x16_bf16(Ar[i & 1][2], Br[(i + (OFF)) & 3][1], acc[2][1], 0, 0, 0); \
            acc[3][0] = __builtin_amdgcn_mfma_f32_32x32x16_bf16(Ar[i & 1][3], Br[(i + (OFF)) & 3][0], acc[3][0], 0, 0, 0); \
            acc[3][1] = __builtin_amdgcn_mfma_f32_32x32x16_bf16(Ar[i & 1][3], Br[(i + (OFF)) & 3][1], acc[3][1], 0, 0, 0); \
            __builtin_amdgcn_s_setprio(0);                                     \
        }                                                                      \
    }

template<int IC, int OC>
__global__ __launch_bounds__(256, 2) void conv3_k(const u16* __restrict__ base,
                                                  u32 in_off,
                                                  const u16* __restrict__ wp,
                                                  const float* __restrict__ bias,
                                                  u32 zp_off,
                                                  u16* __restrict__ outp,
                                                  float* __restrict__ statp) {
    constexpr int KC = IC / 32;         // 8 or 16 — even (required by 2x unroll)
    constexpr int W  = 130;             // 128 px + halo
    constexpr int TU = 12 * W;          // 1560 16B staging units per buffer
    constexpr int NFULL = TU / 256;     // 6
    constexpr int REM   = TU % 256;     // 24
    __shared__ u16 lA0[TU * 8];
    __shared__ u16 lA1[TU * 8];

    int bx0 = blockIdx.x;
    int bx = ((bx0 & 7) << 7) + (bx0 >> 3);   // XCD swizzle (1024 % 8 == 0)
    int y = bx & 127, n = bx >> 7;
    int ocb = blockIdx.y;
    int t = threadIdx.x, lane = t & 63, wv = t >> 6;
    int lm = lane & 31, h = lane >> 5;
    int ocw = ocb * 256 + wv * 64;

    // per-lane staging source offsets (u16 units from `base`)
    u32 off[NFULL + 1];
#pragma unroll
    for (int i = 0; i <= NFULL; ++i) {
        int u = (i == NFULL) ? (NFULL * 256 + lane) : (i * 256 + t);
        int icq = u / (3 * W);
        int r2  = u - icq * (3 * W);
        int dy  = r2 / W;
        int xx  = r2 - dy * W;
        int gy = y - 1 + dy, gx = xx - 1;
        bool ok = ((unsigned)gy < 128u) && ((unsigned)gx < 128u);
        off[i] = ok ? (in_off + (u32)((n * 128 + gy) * 128 + gx) * IC + (icq & 3) * 8)
                    : zp_off;
    }

    auto stage = [&](u16* dst, int kc) {
#pragma unroll
        for (int i = 0; i < NFULL; ++i)
            gl16(base + off[i] + kc * 32, dst + (i * 256 + wv * 64) * 8);
        if (wv == 0 && lane < REM)
            gl16(base + off[NFULL] + kc * 32, dst + NFULL * 256 * 8);
    };

    u32 wboff = (u32)(ocw + lm) * 16 + h * 8;
    bf16x8 Ar[2][4];
    bf16x8 Br[4][2];

    // B loader for subk j (0..17) of chunk kcv
    auto bload = [&](bf16x8* dst, int j, int kcv) {
        int jdy = j / 6, jdx = (j % 6) >> 1, js = j & 1;
        const u16* wb = wp + wboff
            + (u32)(((jdy * 3 + jdx) * KC + kcv) * 2 + js) * (OC * 16);
        dst[0] = *(const bf16x8*)wb;
        dst[1] = *(const bf16x8*)(wb + 512);
    };

    // prologue: subks 0,1,2 of kc=0 into slots 0,1,2 (OFF=0)
    bload(Br[0], 0, 0);
    bload(Br[1], 1, 0);
    bload(Br[2], 2, 0);

    f32x16 acc[4][2];
#pragma unroll
    for (int mf = 0; mf < 4; ++mf)
#pragma unroll
        for (int nf = 0; nf < 2; ++nf)
#pragma unroll
            for (int r = 0; r < 16; ++r) acc[mf][nf][r] = 0.f;

    stage(lA0, 0);
    for (int kcb = 0; kcb < KC; kcb += 2) {
        KCITER(kcb, 0);
        KCITER(kcb + 1, 2);
    }

    long rowb = (long)(n * 128 + y) * 128;
    float ss[2] = {0.f, 0.f}, qq[2] = {0.f, 0.f};
#pragma unroll
    for (int nf = 0; nf < 2; ++nf) {
        int oc = ocw + nf * 32 + lm;
        float bi = bias[oc];
#pragma unroll
        for (int mf = 0; mf < 4; ++mf)
#pragma unroll
            for (int r = 0; r < 16; ++r) {
                int px = mf * 32 + (r & 3) + ((r >> 2) << 3) + (h << 2);
                u16 bv = f2bf(acc[mf][nf][r] + bi);
                outp[(rowb + px) * OC + oc] = bv;
                float vr = bf2f(bv);
                ss[nf] += vr;
                qq[nf] += vr * vr;
            }
    }
#pragma unroll
    for (int nf = 0; nf < 2; ++nf) {
        ss[nf] += __shfl_xor(ss[nf], 32);
        qq[nf] += __shfl_xor(qq[nf], 32);
    }
    if (h == 0) {
#pragma unroll
        for (int nf = 0; nf < 2; ++nf) {
            int oc = ocw + nf * 32 + lm;
            atomicAdd(&statp[oc * 2],     ss[nf]);
            atomicAdd(&statp[oc * 2 + 1], qq[nf]);
        }
    }
}

// Stage 2: per-channel affine (a, b): a*x+b == BN(x), from fused partials.
template<int C>
__global__ __launch_bounds__(256) void stats2_k(const float* __restrict__ part,
                                                const float* __restrict__ g,
                                                const float* __restrict__ be,
                                                float* __restrict__ ab) {
    int ch = blockIdx.x * 256 + threadIdx.x;
    if (ch >= C) return;
    float s = part[ch * 2], q = part[ch * 2 + 1];
    const float M = 131072.f;
    float mean = s / M;
    float var = q / M - mean * mean;
    float a = g[ch] * rsqrtf(var + 1e-5f);
    ab[ch * 2]     = a;
    ab[ch * 2 + 1] = be[ch] - mean * a;
}

// BN1 + ReLU in place on h1 (NHWC bf16, C=512). 8 elems/thread.
__global__ __launch_bounds__(256) void bn_relu_k(u16* __restrict__ h,
                                                 const float* __restrict__ ab) {
    long idx8 = (long)blockIdx.x * 256 + threadIdx.x;
    u16* p = h + idx8 * 8;
    uint4 v = *(const uint4*)p;
    int chb = ((int)idx8 & 63) << 3;
    u32 w[4] = {v.x, v.y, v.z, v.w};
    u32 o[4];
#pragma unroll
    for (int q = 0; q < 4; ++q) {
        int ch = chb + q * 2;
        float2 a0 = *(const float2*)(ab + ch * 2);
        float2 a1 = *(const float2*)(ab + ch * 2 + 2);
        float f0 = bf2f((u16)(w[q] & 0xffff));
        float f1 = bf2f((u16)(w[q] >> 16));
        f0 = fmaxf(f0 * a0.x + a0.y, 0.f);
        f1 = fmaxf(f1 * a1.x + a1.y, 0.f);
        o[q] = (u32)f2bf(f0) | ((u32)f2bf(f1) << 16);
    }
    *(uint4*)p = make_uint4(o[0], o[1], o[2], o[3]);
}

// ---------------------------------------------------------------------------
// Fused BN2+ReLU + 1x1 inverse conv via MFMA (M=131072 px, N=32 oc, K=256).
// ---------------------------------------------------------------------------
__global__ __launch_bounds__(256) void inv_conv_k(const u16* __restrict__ h2,
                                                  const float* __restrict__ ab,
                                                  const float* __restrict__ winv,
                                                  const float* __restrict__ binv,
                                                  float* __restrict__ out) {
    __shared__ float lab[512];
    int t = threadIdx.x, lane = t & 63, wv = t >> 6;
    int lm = lane & 31, h = lane >> 5;
    lab[t] = ab[t];
    lab[t + 256] = ab[t + 256];
    __syncthreads();

    // B fragments: B[s] element j = w_inv[oc=lm][k = s*16 + h*8 + j]
    bf16x8 B[16];
#pragma unroll
    for (int s = 0; s < 16; ++s) {
        const float* wsrc = winv + lm * 256 + s * 16 + h * 8;
        union { bf16x8 v; u16 a[8]; } cv;
#pragma unroll
        for (int j = 0; j < 8; ++j) cv.a[j] = f2bf(wsrc[j]);
        B[s] = cv.v;
    }

    long pxw = (long)blockIdx.x * 256 + wv * 64;
    const u16* a0p = h2 + (pxw + lm) * 256 + h * 8;
    const u16* a1p = a0p + 32 * 256;

    f32x16 acc0, acc1;
#pragma unroll
    for (int r = 0; r < 16; ++r) { acc0[r] = 0.f; acc1[r] = 0.f; }

#pragma unroll
    for (int s = 0; s < 16; ++s) {
        int k0 = s * 16 + h * 8;
        uint4 v0 = *(const uint4*)(a0p + s * 16);
        uint4 v1 = *(const uint4*)(a1p + s * 16);
        u32 w0[4] = {v0.x, v0.y, v0.z, v0.w};
        u32 w1[4] = {v1.x, v1.y, v1.z, v1.w};
        union { bf16x8 v; u16 a[8]; } A0, A1;
#pragma unroll
        for (int j = 0; j < 8; ++j) {
            float aab = lab[(k0 + j) * 2], bbb = lab[(k0 + j) * 2 + 1];
            u16 u0 = (j & 1) ? (u16)(w0[j >> 1] >> 16) : (u16)(w0[j >> 1] & 0xffff);
            u16 u1 = (j & 1) ? (u16)(w1[j >> 1] >> 16) : (u16)(w1[j >> 1] & 0xffff);
            A0.a[j] = f2bf(fmaxf(bf2f(u0) * aab + bbb, 0.f));
            A1.a[j] = f2bf(fmaxf(bf2f(u1) * aab + bbb, 0.f));
        }
        acc0 = __builtin_amdgcn_mfma_f32_32x32x16_bf16(A0.v, B[s], acc0, 0, 0, 0);
        acc1 = __builtin_amdgcn_mfma_f32_32x32x16_bf16(A1.v, B[s], acc1, 0, 0, 0);
    }

    float bi = binv[lm];
    int n = (int)(pxw >> 14);
    int prem = (int)(pxw & 16383);
    float* ob = out + (((long)(n * 32 + lm)) << 14) + prem + 4 * h;
#pragma unroll
    for (int g = 0; g < 4; ++g) {
        f32x4 o0, o1;
#pragma unroll
        for (int i = 0; i < 4; ++i) { o0[i] = acc0[g * 4 + i] + bi; o1[i] = acc1[g * 4 + i] + bi; }
        *(f32x4*)(ob + g * 8)      = o0;
        *(f32x4*)(ob + 32 + g * 8) = o1;
    }
}

// ---------------------------------------------------------------------------
// Workspace layout (bytes) — ~200 MiB:
//   0         w1p   (2,359,296)
//   2359296   w2p   (2,359,296)
//   4718592   part1 (4,096)  fused BN1 stats (s,q per oc)
//   4722688   part2 (2,048)  fused BN2 stats
//   5242880   ab1   (4,096)
//   5246976   ab2   (2,048)
//   5249024   zp    (1,024)  zero page for conv halo
//   8388608   coeffs / h2 (67,108,864)
//   75497472  h1    (134,217,728)
// ---------------------------------------------------------------------------
extern "C" void kernel_launch(void* const* d_in, const int* in_sizes, int n_in,
                              void* d_out, int out_size, void* d_ws, size_t ws_size,
                              hipStream_t stream) {
    const float* x     = (const float*)d_in[0];
    const float* w_dir = (const float*)d_in[1];
    const float* w1    = (const float*)d_in[2];
    const float* b1    = (const float*)d_in[3];
    const float* g1    = (const float*)d_in[4];
    const float* be1   = (const float*)d_in[5];
    const float* w2    = (const float*)d_in[6];
    const float* b2    = (const float*)d_in[7];
    const float* g2    = (const float*)d_in[8];
    const float* be2   = (const float*)d_in[9];
    const float* w_inv = (const float*)d_in[10];
    const float* b_inv = (const float*)d_in[11];
    float* out = (float*)d_out;
    char* ws = (char*)d_ws;

    u16*   w1p   = (u16*)(ws + 0);
    u16*   w2p   = (u16*)(ws + 2359296);
    float* part1 = (float*)(ws + 4718592);
    float* part2 = (float*)(ws + 4722688);
    float* ab1   = (float*)(ws + 5242880);
    float* ab2   = (float*)(ws + 5246976);
    u16*   zp    = (u16*)(ws + 5249024);
    u16*   coef  = (u16*)(ws + 8388608);     // also h2
    u16*   h1    = (u16*)(ws + 75497472);
    const u16* basep = (const u16*)ws;
    u32 zp_off   = 5249024 / 2;
    u32 coef_off = 8388608 / 2;
    u32 h1_off   = 75497472 / 2;

    hipMemsetAsync(zp, 0, 1024, stream);
    hipMemsetAsync(part1, 0, 8192, stream);   // covers part1 + part2
    repack_w_k<<<4608, 256, 0, stream>>>(w1, w1p, 512, 256, 1179648);
    repack_w_k<<<4608, 256, 0, stream>>>(w2, w2p, 256, 512, 1179648);
    dir_conv_k<<<4096, 256, 0, stream>>>(x, w_dir, coef);
    conv3_k<256, 512><<<dim3(1024, 2), 256, 0, stream>>>(basep, coef_off, w1p, b1, zp_off, h1, part1);
    stats2_k<512><<<2, 256, 0, stream>>>(part1, g1, be1, ab1);
    bn_relu_k<<<32768, 256, 0, stream>>>(h1, ab1);
    conv3_k<512, 256><<<dim3(1024, 1), 256, 0, stream>>>(basep, h1_off, w2p, b2, zp_off, coef, part2);
    stats2_k<256><<<1, 256, 0, stream>>>(part2, g2, be2, ab2);
    inv_conv_k<<<512, 256, 0, stream>>>(coef, ab2, w_inv, b_inv, out);
}